// Round 19
// baseline (499.620 us; speedup 1.0000x reference)
//
#include <hip/hip_runtime.h>
#include <cstddef>

typedef _Float16 f16;
typedef f16 f16x4 __attribute__((ext_vector_type(4)));
typedef f16 f16x8 __attribute__((ext_vector_type(8)));
typedef float f32x4 __attribute__((ext_vector_type(4)));

// async global->LDS, 16B per lane. LDS dest = uniform base + lane*16 (HW);
// global src is per-lane.
__device__ inline void gld_lds16(const f16* g, f16* l) {
    __builtin_amdgcn_global_load_lds(
        (const __attribute__((address_space(1))) void*)g,
        (__attribute__((address_space(3))) void*)l, 16, 0, 0);
}

// ---------------------------------------------------------------------------
// 16x16x32 MFMA submanifold conv, A-direct / B-in-LDS.
//  - COMPOSED SCORE CHAINS (R19): x,y are single-use -> conv+score compose:
//    G[R][2k2+c] = sum_k1 f[nbr(R,k1)] @ (Wconv[k1] @ Ws[k2]); scores(S) =
//    sum_k2 G[nbr(S,k2)][2k2+c]. Level-1/2 convs now CO=54(pad 64), CS=1.
//  - GEOMETRY (R5..R18 measured): MROW>1 always loses; conv2 dbuf BMODE=1
//    WAVES=8; conv1 sbuf BMODE=2 WAVES=4; conv3/head whole-B BMODE=0.
//  - MASK REMAP (R13) + SKIPZ (R17, -95us): nbr remapped so masked gathers
//    hit the zero row; a wave whose entire 16-row A-tile is the zero row
//    skips A-loads + ds_reads + MFMAs for that k (exact; barriers kept).
//  - TERMS=2: Markidis f16 split (hi + lo*2^12), 3 MFMAs/pair -> ~fp32
//    accuracy (mask-threshold chain). TERMS=1: plain f16 (points chain).
//  - Bijective XCD-chunk swizzle (nwg % 8 == 0).
// ---------------------------------------------------------------------------
template<int C, int NTB, int CS, int WCO, int TERMS, int WAVES, int BMODE,
         int OUTM, int PIPEA, int MROW, int SKIPZ>
__global__ __launch_bounds__(WAVES * 64)
void conv_mfma(const f16* __restrict__ fin, size_t in_plane,
               const int* __restrict__ nbr,
               const f16* __restrict__ Wb,
               void* __restrict__ outv, int ostride, int ooff, size_t out_plane,
               int CO_real, int N, int Nstore, int tilesPad)
{
    constexpr int KK   = C / 32;
    constexpr int KKL  = (TERMS == 2) ? KK : 1;
    constexpr int NTBT = WCO * NTB;
    constexpr int CH   = KK * NTBT * TERMS;
    constexpr int WROW = WAVES / WCO;
    constexpr int ROWS = WROW * MROW * 16;
    constexpr int BUFS = (BMODE == 0) ? 27 : ((BMODE == 1) ? 2 : 1);
    __shared__ f16 sB[BUFS * CH * 512];

    const int lane = threadIdx.x & 63;
    const int w    = threadIdx.x >> 6;
    const int wco  = w % WCO;
    const int wrow = w / WCO;
    int gid = blockIdx.x;
    { const int q = (tilesPad * CS) >> 3; gid = (gid & 7) * q + (gid >> 3); }
    const int tile = gid / CS;
    const int cs   = gid - tile * CS;
    const int n0   = tile * ROWS;
    const int NZ   = N;                          // zero row
    const int h8   = (lane >> 4) * 8;

    int  site[MROW];
    bool sv[MROW];
#pragma unroll
    for (int r = 0; r < MROW; ++r) {
        site[r] = n0 + (wrow * MROW + r) * 16 + (lane & 15);
        sv[r]   = site[r] < N;
    }

    auto nbrIdx = [&](int r, int k) -> int {
        int v = sv[r] ? nbr[(size_t)site[r] * 27 + k] : -1;
        return (v < 0) ? NZ : v;
    };

    // Wave-uniform: true iff every gathered row of this wave is the zero row.
    auto allNZ = [&](const int* ix) -> bool {
        if constexpr (!SKIPZ) return false;
        int m = 1;
#pragma unroll
        for (int r = 0; r < MROW; ++r) m &= (ix[r] == NZ);
        return __all(m);
    };

    auto stageK = [&](int k, int buf) {
        const f16* src = Wb + ((size_t)(k * CS + cs) * CH) * 512 + lane * 8;
        f16* dst = &sB[(size_t)buf * CH * 512];
#pragma unroll
        for (int c = w; c < CH; c += WAVES)
            gld_lds16(src + (size_t)c * 512, dst + (size_t)c * 512);
    };

    f32x4 acc[MROW * NTB], acc2[MROW * NTB];
#pragma unroll
    for (int i = 0; i < MROW * NTB; ++i) {
        acc[i]  = (f32x4){0.f, 0.f, 0.f, 0.f};
        acc2[i] = (f32x4){0.f, 0.f, 0.f, 0.f};
    }

    f16x8 va[MROW * KK], vl[MROW * KKL];
    f16x8 vaB[(BMODE == 0 && PIPEA) ? MROW * KK : 1];
    f16x8 vlB[(BMODE == 0 && PIPEA) ? MROW * KKL : 1];

    auto loadA = [&](int idx, f16x8* pva, f16x8* pvl) {
        const f16* arow = fin + (size_t)idx * C + h8;
#pragma unroll
        for (int kk = 0; kk < KK; ++kk) {
            pva[kk] = *(const f16x8*)(arow + kk * 32);
            if constexpr (TERMS == 2)
                pvl[kk] = *(const f16x8*)(arow + in_plane + kk * 32);
        }
    };

    auto mfmaPhase = [&](const f16x8* pva, const f16x8* pvl, int kbuf) {
        const f16* sBc = &sB[(size_t)kbuf * CH * 512] + lane * 8;
#pragma unroll
        for (int kk = 0; kk < KK; ++kk) {
#pragma unroll
            for (int nt = 0; nt < NTB; ++nt) {
                const f16* bp = sBc + (size_t)((kk * NTBT + wco * NTB + nt) * TERMS) * 512;
                const f16x8 bh = *(const f16x8*)bp;
                if constexpr (TERMS == 2) {
                    const f16x8 bl = *(const f16x8*)(bp + 512);
#pragma unroll
                    for (int r = 0; r < MROW; ++r) {
                        acc[r * NTB + nt]  = __builtin_amdgcn_mfma_f32_16x16x32_f16(
                            pva[r * KK + kk], bh, acc[r * NTB + nt], 0, 0, 0);
                        acc2[r * NTB + nt] = __builtin_amdgcn_mfma_f32_16x16x32_f16(
                            pva[r * KK + kk], bl, acc2[r * NTB + nt], 0, 0, 0);
                        acc2[r * NTB + nt] = __builtin_amdgcn_mfma_f32_16x16x32_f16(
                            pvl[r * KK + kk], bh, acc2[r * NTB + nt], 0, 0, 0);
                    }
                } else {
#pragma unroll
                    for (int r = 0; r < MROW; ++r)
                        acc[r * NTB + nt] = __builtin_amdgcn_mfma_f32_16x16x32_f16(
                            pva[r * KK + kk], bh, acc[r * NTB + nt], 0, 0, 0);
                }
            }
        }
    };

    if constexpr (BMODE == 1) {
        // ---- per-k dbuf; 1 barrier/k; A(k+1) issued pre-drain; SKIPZ ----
        int idxN[MROW];
        bool skipC, skipN;
        {
            int idx0[MROW];
#pragma unroll
            for (int r = 0; r < MROW; ++r) idx0[r] = nbrIdx(r, 0);
            skipC = allNZ(idx0);
            if (!skipC)
#pragma unroll
                for (int r = 0; r < MROW; ++r)
                    loadA(idx0[r], &va[r * KK], &vl[r * KKL]);
        }
        stageK(0, 0);
#pragma unroll
        for (int r = 0; r < MROW; ++r) idxN[r] = nbrIdx(r, 1);
        skipN = allNZ(idxN);
        __syncthreads();

        for (int k = 0; k < 27; ++k) {
            if (k + 1 < 27) stageK(k + 1, (k + 1) & 1);
            if (!skipC) mfmaPhase(va, vl, k & 1);
            if (k + 1 < 27) {
                if (!skipN)
#pragma unroll
                    for (int r = 0; r < MROW; ++r)
                        loadA(idxN[r], &va[r * KK], &vl[r * KKL]);
                skipC = skipN;
#pragma unroll
                for (int r = 0; r < MROW; ++r)
                    idxN[r] = (k + 2 < 27) ? nbrIdx(r, k + 2) : NZ;
                skipN = allNZ(idxN);
                __syncthreads();
            }
        }
    } else if constexpr (BMODE == 2) {
        // ---- per-k single buffer; 2 barriers/k (covered by co-res blocks) ----
        int idxN[MROW];
#pragma unroll
        for (int r = 0; r < MROW; ++r)
            loadA(nbrIdx(r, 0), &va[r * KK], &vl[r * KKL]);
#pragma unroll
        for (int r = 0; r < MROW; ++r) idxN[r] = nbrIdx(r, 1);

        for (int k = 0; k < 27; ++k) {
            stageK(k, 0);
            __syncthreads();
            mfmaPhase(va, vl, 0);
            if (k + 1 < 27) {
#pragma unroll
                for (int r = 0; r < MROW; ++r)
                    loadA(idxN[r], &va[r * KK], &vl[r * KKL]);
#pragma unroll
                for (int r = 0; r < MROW; ++r)
                    idxN[r] = (k + 2 < 27) ? nbrIdx(r, k + 2) : NZ;
                __syncthreads();
            }
        }
    } else {
        // ---- whole-B resident, no k-loop barriers; PIPEA A reg-dbuf; SKIPZ ----
#pragma unroll
        for (int c = w; c < 27 * CH; c += WAVES)
            gld_lds16(Wb + (size_t)c * 512 + lane * 8, &sB[(size_t)c * 512]);
        int idxN[MROW];
        bool skipC, skipN;
        {
            int idx0[MROW];
#pragma unroll
            for (int r = 0; r < MROW; ++r) idx0[r] = nbrIdx(r, 0);
            skipC = allNZ(idx0);
            if (!skipC)
#pragma unroll
                for (int r = 0; r < MROW; ++r)
                    loadA(idx0[r], &va[r * KK], &vl[r * KKL]);
        }
#pragma unroll
        for (int r = 0; r < MROW; ++r) idxN[r] = nbrIdx(r, 1);
        skipN = allNZ(idxN);
        __syncthreads();

        if constexpr (PIPEA) {
            auto body = [&](int k, f16x8* vac, f16x8* vlc, f16x8* van, f16x8* vln) {
                if (k >= 27) return;
                bool nextC = skipN;
                if (k + 1 < 27) {
                    if (!skipN)
#pragma unroll
                        for (int r = 0; r < MROW; ++r)
                            loadA(idxN[r], &van[r * KK], &vln[r * KKL]);
#pragma unroll
                    for (int r = 0; r < MROW; ++r)
                        idxN[r] = (k + 2 < 27) ? nbrIdx(r, k + 2) : NZ;
                    skipN = allNZ(idxN);
                }
                if (!skipC) mfmaPhase(vac, vlc, k);
                skipC = nextC;
            };
            for (int k2 = 0; k2 < 27; k2 += 2) {
                body(k2, va, vl, vaB, vlB);
                body(k2 + 1, vaB, vlB, va, vl);
            }
        } else {
            for (int k = 0; k < 27; ++k) {
                if (!skipC) mfmaPhase(va, vl, k);
                if (k + 1 < 27) {
                    if (!skipN)
#pragma unroll
                        for (int r = 0; r < MROW; ++r)
                            loadA(idxN[r], &va[r * KK], &vl[r * KKL]);
                    skipC = skipN;
#pragma unroll
                    for (int r = 0; r < MROW; ++r)
                        idxN[r] = (k + 2 < 27) ? nbrIdx(r, k + 2) : NZ;
                    skipN = allNZ(idxN);
                }
            }
        }
    }

    // ---- epilogue: D col=lane&15, row=(lane>>4)*4+j ----
    const int colg = lane & 15;
    const int rg   = lane >> 4;
#pragma unroll
    for (int r = 0; r < MROW; ++r) {
#pragma unroll
        for (int nt = 0; nt < NTB; ++nt) {
#pragma unroll
            for (int j = 0; j < 4; ++j) {
                float v = acc[r * NTB + nt][j];
                if constexpr (TERMS == 2) v += acc2[r * NTB + nt][j] * (1.f / 4096.f);
                const int n  = n0 + (wrow * MROW + r) * 16 + rg * 4 + j;
                const int co = ((cs * WCO + wco) * NTB + nt) * 16 + colg;
                if (n < Nstore && co < CO_real) {
                    if constexpr (OUTM == 0) {
                        ((float*)outv)[(size_t)n * ostride + ooff + co] = v;
                    } else if constexpr (OUTM == 1) {
                        ((f16*)outv)[(size_t)n * ostride + co] = (f16)v;
                    } else {
                        f16* o = (f16*)outv;
                        const f16 h = (f16)v;
                        o[(size_t)n * ostride + co] = h;
                        o[out_plane + (size_t)n * ostride + co] = (f16)((v - (float)h) * 4096.f);
                    }
                }
            }
        }
    }
}

// nbrm[i] = nbr[i] if that neighbor survives the attention mask, else -1.
__global__ __launch_bounds__(256)
void remap_nbr(const int* __restrict__ nbr, const float* __restrict__ att,
               int* __restrict__ nbrm, size_t total)
{
    const size_t i = (size_t)blockIdx.x * 256 + threadIdx.x;
    if (i >= total) return;
    const int j = nbr[i];
    nbrm[i] = (j >= 0 && att[j] > 0.5f) ? j : -1;
}

// zmask[site] = 1 iff site has any surviving (non-remapped) neighbor.
__global__ __launch_bounds__(256)
void zmask_kernel(const int* __restrict__ nbrm, int* __restrict__ zm, int N)
{
    const int site = blockIdx.x * 256 + threadIdx.x;
    if (site >= N) return;
    int any = 0;
#pragma unroll
    for (int k = 0; k < 27; ++k)
        any |= (nbrm[(size_t)site * 27 + k] >= 0);
    zm[site] = any;
}

// nbrz[i] = nbr[i] if z[nbr[i]] is nonzero (per zmask), else -1.
__global__ __launch_bounds__(256)
void remap_nbr_zm(const int* __restrict__ nbr, const int* __restrict__ zm,
                  int* __restrict__ nbrz, size_t total)
{
    const size_t i = (size_t)blockIdx.x * 256 + threadIdx.x;
    if (i >= total) return;
    const int j = nbr[i];
    nbrz[i] = (j >= 0 && zm[j]) ? j : -1;
}

// Composed weights: V[k1][ci][2*k2+c] = sum_ci2 Wc[k1][ci][ci2]*Ws[k2][ci2][c]
// (fp32 exact composition of conv+score weights; 27*C*54 outputs).
__global__ __launch_bounds__(256)
void compose_v(const float* __restrict__ Wc, const float* __restrict__ Ws,
               float* __restrict__ V, int C)
{
    const int total = 27 * C * 54;
    const int t = blockIdx.x * blockDim.x + threadIdx.x;
    if (t >= total) return;
    const int slot = t % 54;
    const int ci   = (t / 54) % C;
    const int k1   = t / (54 * C);
    const int k2   = slot >> 1;
    const int c    = slot & 1;
    const float* wc = Wc + ((size_t)k1 * C + ci) * C;
    const float* ws = Ws + (size_t)k2 * C * 2 + c;
    float s = 0.f;
    for (int ci2 = 0; ci2 < C; ++ci2)
        s += wc[ci2] * ws[(size_t)ci2 * 2];
    V[t] = s;
}

// scores(S) = sum_k2 G[nbr(S,k2)][2*k2+c]; G rows are [64]-strided f32.
// Also fills the coords columns of ppn.
__global__ __launch_bounds__(256)
void reduce_g(const float* __restrict__ G, const int* __restrict__ nbr,
              const int* __restrict__ coords, float* __restrict__ ppn, int N)
{
    const int site = blockIdx.x * 256 + threadIdx.x;
    if (site >= N) return;
    float s0 = 0.f, s1 = 0.f;
#pragma unroll
    for (int k = 0; k < 27; ++k) {
        const int idx = nbr[(size_t)site * 27 + k];
        if (idx >= 0) {
            const float2 p = *(const float2*)(G + (size_t)idx * 64 + 2 * k);
            s0 += p.x; s1 += p.y;
        }
    }
    float* row = ppn + (size_t)site * 6;
    const int* cr = coords + (size_t)site * 4;
    row[0] = (float)cr[0]; row[1] = (float)cr[1];
    row[2] = (float)cr[2]; row[3] = (float)cr[3];
    row[4] = s0; row[5] = s1;
}

// ---------------------------------------------------------------------------
// Pre-pass: f32 rows (optionally x att-mask) -> f16 split planes, plus a
// zero row at index N. SPARSE=1: rows with att==0 skipped (unreachable).
// ---------------------------------------------------------------------------
template<int TERMS, int SPARSE>
__global__ __launch_bounds__(256)
void prepass(const float* __restrict__ f, const float* __restrict__ att,
             f16* __restrict__ dst, size_t plane, int C4, int N)
{
    const size_t i = (size_t)blockIdx.x * 256 + threadIdx.x;
    const size_t total = (size_t)(N + 1) * C4;
    if (i >= total) return;
    const int row = (int)(i / C4);
    float4 v = make_float4(0.f, 0.f, 0.f, 0.f);
    if (row < N) {
        float a = 1.f;
        if (att != nullptr) {
            a = att[row];
            if (SPARSE && a == 0.f) return;   // row unreachable: skip entirely
        }
        v = *(const float4*)(f + i * 4);
        v.x *= a; v.y *= a; v.z *= a; v.w *= a;
    }
    const float xs[4] = {v.x, v.y, v.z, v.w};
    f16x4 hi, lo;
#pragma unroll
    for (int j = 0; j < 4; ++j) {
        const f16 h = (f16)xs[j];
        hi[j] = h;
        lo[j] = (f16)((xs[j] - (float)h) * 4096.f);
    }
    *(f16x4*)(dst + i * 4) = hi;
    if constexpr (TERMS == 2)
        *(f16x4*)(dst + plane + i * 4) = lo;
}

// Pack fp32 W[27][C][CO_real] into 16x16 fragment chunks:
// chunk id = ((((k*CS + cs)*KK + kk)*NTB + nt)*TERMS + term), 512 f16 each.
__global__ __launch_bounds__(256)
void pack_w_f16(const float* __restrict__ W, f16* __restrict__ Wb,
                int C, int CO_real, int CS, int NTB, int TERMS)
{
    const int KK = C / 32;
    const int total = 27 * CS * KK * NTB * TERMS * 64;
    const int t = blockIdx.x * blockDim.x + threadIdx.x;
    if (t >= total) return;
    const int lane = t & 63;
    int cid = t >> 6;
    const int term = cid % TERMS; cid /= TERMS;
    const int nt   = cid % NTB;   cid /= NTB;
    const int kk   = cid % KK;    cid /= KK;
    const int cs   = cid % CS;
    const int k    = cid / CS;
    const int co   = (cs * NTB + nt) * 16 + (lane & 15);
#pragma unroll
    for (int j = 0; j < 8; ++j) {
        const int ci = kk * 32 + (lane >> 4) * 8 + j;
        const float x = (co < CO_real) ? W[((size_t)k * C + ci) * CO_real + co] : 0.f;
        const f16 h = (f16)x;
        Wb[(size_t)t * 8 + j] = (term == 0) ? h : (f16)((x - (float)h) * 4096.f);
    }
}

// Pack the fused head [27][32][{3|2|5}->10] directly into fragment chunks
// (chunk per k; single term).
__global__ __launch_bounds__(256)
void pack_wh_frag(const float* __restrict__ wp, const float* __restrict__ ws,
                  const float* __restrict__ wt, f16* __restrict__ Wb)
{
    const int t = blockIdx.x * blockDim.x + threadIdx.x;
    if (t >= 27 * 64) return;
    const int lane = t & 63;
    const int k    = t >> 6;
    const int co   = lane & 15;
#pragma unroll
    for (int j = 0; j < 8; ++j) {
        const int ci = (lane >> 4) * 8 + j;
        float x = 0.f;
        if (co < 3)       x = wp[((size_t)k * 32 + ci) * 3 + co];
        else if (co < 5)  x = ws[((size_t)k * 32 + ci) * 2 + (co - 3)];
        else if (co < 10) x = wt[((size_t)k * 32 + ci) * 5 + (co - 5)];
        Wb[(size_t)t * 8 + j] = (f16)x;
    }
}

__global__ __launch_bounds__(256)
void att_kernel(const float* __restrict__ ppn, const int* __restrict__ parent,
                float* __restrict__ att, int N)
{
    const int i = blockIdx.x * blockDim.x + threadIdx.x;
    if (i >= N) return;
    const int p = parent[i];
    const float s0 = ppn[(size_t)p * 6 + 4];
    const float s1 = ppn[(size_t)p * 6 + 5];
    const float m  = fmaxf(s0, s1);
    const float e0 = expf(s0 - m);
    const float e1 = expf(s1 - m);
    const float p1 = e1 / (e0 + e1);
    att[i] = (p1 > 0.8f) ? 1.f : 0.f;
}

extern "C" void kernel_launch(void* const* d_in, const int* in_sizes, int n_in,
                              void* d_out, int out_size, void* d_ws, size_t ws_size,
                              hipStream_t stream)
{
    const float* f1       = (const float*)d_in[0];
    const float* f2       = (const float*)d_in[1];
    const float* f3       = (const float*)d_in[2];
    const float* w1_conv  = (const float*)d_in[3];
    const float* w1_score = (const float*)d_in[4];
    const float* w2_conv  = (const float*)d_in[5];
    const float* w2_score = (const float*)d_in[6];
    const float* w3_conv  = (const float*)d_in[7];
    const float* w3_pix   = (const float*)d_in[8];
    const float* w3_score = (const float*)d_in[9];
    const float* w3_type  = (const float*)d_in[10];
    const int* coords1    = (const int*)d_in[11];
    const int* coords2    = (const int*)d_in[12];
    const int* nbr1       = (const int*)d_in[13];
    const int* nbr2       = (const int*)d_in[14];
    const int* nbr3       = (const int*)d_in[15];
    const int* parent12   = (const int*)d_in[16];
    const int* parent23   = (const int*)d_in[17];

    const int N1 = in_sizes[0] / 160;   // 20000
    const int N2 = in_sizes[1] / 96;    // 160000
    const int N3 = in_sizes[2] / 32;    // 320000

    // Output layout: points[N3,10] | ppn1[N1,6] | ppn2[N2,6] | att[N2] | att2[N3]
    float* points = (float*)d_out;
    float* ppn1   = points + (size_t)N3 * 10;
    float* ppn2   = ppn1 + (size_t)N1 * 6;
    float* attn   = ppn2 + (size_t)N2 * 6;
    float* attn2  = attn + (size_t)N2;

    // Workspace regions (A: 2*p1, B: 2*p1, C: 2*p2, D: 2*p2, then weights).
    const size_t p1 = (size_t)(N1 + 1) * 160;
    const size_t p2 = (size_t)(N2 + 1) * 96;
    const size_t p3 = (size_t)(N3 + 1) * 32;
    f16* f1s  = (f16*)d_ws;           // region A (12.8MB): f1 split
    f16* regB = f1s + 2 * p1;         // region B (12.8MB)
    f16* f2s  = regB + 2 * p1;        // region C (61.4MB): f2 split -> zs+nbr3m
    f16* regD = f2s + 2 * p2;         // region D (61.4MB): G2 -> zmask+nbr3z
    float* G1 = (float*)regB;         // [N1][64] f32 = 5.1MB (conv1G -> reduce1)
    int* nbr2m = (int*)f1s;           // 17.3MB spans A+B (after reduce1)
    f16* f3s  = f1s;                  // 20.5MB spans A+B (after conv2G)
    float* G2 = (float*)regD;         // [N2][64] f32 = 41MB (conv2G -> reduce2)
    f16* zs   = f2s;                  // 20.5MB (region C, after conv2G)
    int* nbr3m = (int*)((char*)f2s + ((p3 * 2 + 255) & ~(size_t)255));
                                      // region C +20.5MB, 34.6MB, ends 55.1
    int* zmask = (int*)regD;          // 1.28MB (after reduce2; G2 dead)
    int* nbr3z = zmask + ((N3 + 64) & ~63);  // 34.6MB, ends ~36MB <= 61.4MB
    f16* Wb1  = regD + 2 * p2;              // 1080 chunks (C=160,NTB=4,CS=1)
    f16* Wb2  = Wb1 + (size_t)1080 * 512;   // 648 chunks (C=96,NTB=4,CS=1)
    f16* Wb3  = Wb2 + (size_t)648 * 512;    // 54
    f16* Wbh  = Wb3 + (size_t)54 * 512;     // 27
    float* V1 = (float*)(Wbh + (size_t)27 * 512);  // 27*160*54 f32 = 0.93MB
    float* V2 = V1 + (size_t)27 * 160 * 54;        // 27*96*54 f32 = 0.56MB

    // ---- weight composition + packing ----
    compose_v<<<(27 * 160 * 54 + 255) / 256, 256, 0, stream>>>(w1_conv, w1_score, V1, 160);
    compose_v<<<(27 * 96 * 54 + 255) / 256, 256, 0, stream>>>(w2_conv, w2_score, V2, 96);
    pack_w_f16<<<(1080 * 64 + 255) / 256, 256, 0, stream>>>(V1, Wb1, 160, 54, 1, 4, 2);
    pack_w_f16<<<(648 * 64 + 255) / 256, 256, 0, stream>>>(V2, Wb2, 96, 54, 1, 4, 2);
    pack_w_f16<<<(54 * 64 + 255) / 256, 256, 0, stream>>>(w3_conv, Wb3, 32, 32, 1, 2, 1);
    pack_wh_frag<<<(27 * 64 + 255) / 256, 256, 0, stream>>>(w3_pix, w3_score, w3_type, Wbh);

    // ---- level 1 (composed conv+score: G1 = conv(f1, V1), CO=54) ----
    prepass<2, 0><<<(int)(((size_t)(N1 + 1) * 40 + 255) / 256), 256, 0, stream>>>(
        f1, nullptr, f1s, p1, 40, N1);
    // C=160 NTB=4 CS=1, sbuf 40KB (4 blocks/CU), WAVES=4. tiles=313 -> pad
    // 320 (%8==0), ROWS=64.
    conv_mfma<160, 4, 1, 1, 2, 4, 2, 0, 0, 1, 0><<<320, 256, 0, stream>>>(
        f1s, p1, nbr1, Wb1, G1, 64, 0, 0, 54, N1, N1, 320);
    reduce_g<<<(N1 + 255) / 256, 256, 0, stream>>>(G1, nbr1, coords1, ppn1, N1);
    att_kernel<<<(N2 + 255) / 256, 256, 0, stream>>>(ppn1, parent12, attn, N2);

    // ---- level 2 (composed, SKIPZ) ----
    remap_nbr<<<(int)(((size_t)N2 * 27 + 255) / 256), 256, 0, stream>>>(
        nbr2, attn, nbr2m, (size_t)N2 * 27);
    prepass<2, 1><<<(int)(((size_t)(N2 + 1) * 24 + 255) / 256), 256, 0, stream>>>(
        f2, attn, f2s, p2, 24, N2);
    // C=96 NTB=4 CS=1, dbuf 48KB (3 blocks/CU), WAVES=8, SKIPZ.
    // ROWS=128, tiles=1250 -> pad 1256 (%8==0).
    conv_mfma<96, 4, 1, 1, 2, 8, 1, 0, 0, 1, 1><<<1256, 512, 0, stream>>>(
        f2s, p2, nbr2m, Wb2, G2, 64, 0, 0, 54, N2, N2, 1256);
    reduce_g<<<(N2 + 255) / 256, 256, 0, stream>>>(G2, nbr2, coords2, ppn2, N2);
    att_kernel<<<(N3 + 255) / 256, 256, 0, stream>>>(ppn2, parent23, attn2, N3);

    // ---- level 3 (points chain, single-term f16; NOT composed: CO would
    //      blow up 32->270) ----
    remap_nbr<<<(int)(((size_t)N3 * 27 + 255) / 256), 256, 0, stream>>>(
        nbr3, attn2, nbr3m, (size_t)N3 * 27);
    zmask_kernel<<<(N3 + 255) / 256, 256, 0, stream>>>(nbr3m, zmask, N3);
    remap_nbr_zm<<<(int)(((size_t)N3 * 27 + 255) / 256), 256, 0, stream>>>(
        nbr3, zmask, nbr3z, (size_t)N3 * 27);
    prepass<1, 1><<<(int)(((size_t)(N3 + 1) * 8 + 255) / 256), 256, 0, stream>>>(
        f3, attn2, f3s, 0, 8, N3);
    // conv3: whole-B, PIPEA, MROW=1 + SKIPZ (input masked by att2).
    conv_mfma<32, 2, 1, 1, 1, 8, 0, 1, 1, 1, 1><<<2504, 512, 0, stream>>>(
        f3s, 0, nbr3m, Wb3, zs, 32, 0, 0, 32, N3, N3 + 1, 2504);
    // head: whole-B, PIPEA, MROW=1 + SKIPZ via z-sparsity (nbr3z).
    conv_mfma<32, 1, 1, 1, 1, 8, 0, 0, 1, 1, 1><<<2504, 512, 0, stream>>>(
        zs, 0, nbr3z, Wbh, points, 10, 0, 0, 10, N3, N3, 2504);
}